// Round 2
// baseline (93.050 us; speedup 1.0000x reference)
//
#include <hip/hip_runtime.h>
#include <hip/hip_bf16.h>
#include <math.h>

#define N 512
#define BIT 64
#define NUM_CLASSES 100
#define ALPHA 5.0f
#define LAM 1.0f

// workspace layout (in d_ws):
//   float acc[0..2] : loss1_sum, valid_count, sum2
//   int   ctr       : blocks-done counter (at byte offset 12)
//   int   labels[N] : at byte offset 64

// ---------------------------------------------------------------------------
// labels from one-hot y. grid 8 x 64 threads, one thread per row.
// ---------------------------------------------------------------------------
__global__ void label_kernel(const float* __restrict__ y,
                             int* __restrict__ labels) {
    int r = blockIdx.x * 64 + threadIdx.x;   // 0..511
    const float* yr = y + (size_t)r * NUM_CLASSES;
    int lbl = 0;
    for (int c = 0; c < NUM_CLASSES; ++c) {
        if (yr[c] > 0.5f) lbl = c;
    }
    labels[r] = lbl;
}

// ---------------------------------------------------------------------------
// fused: one block per row r.
//  - d[n] = dot(u[r], u[n]) computed from L2 (u is 128 KB, L2-resident)
//  - compact positives (lab[n]==lab[r]), loop pos x neg softplus
//  - loss2 share: row r's 64 elements of (u - sign u)^2
//  - last block to finish combines and writes out[0]
// grid 512 x 256 threads
// ---------------------------------------------------------------------------
__global__ void fused_kernel(const float* __restrict__ u,
                             const int* __restrict__ labels,
                             float* __restrict__ acc,
                             int* __restrict__ ctr,
                             float* __restrict__ out) {
    int r = blockIdx.x;
    int tid = threadIdx.x;

    __shared__ float ur[BIT];
    __shared__ float d[N];
    __shared__ int   lab[N];
    __shared__ int   poslist[N];
    __shared__ int   npos_s;
    __shared__ float wsum[4];

    if (tid == 0) npos_s = 0;
    if (tid < BIT) ur[tid] = u[(size_t)r * BIT + tid];
    for (int i = tid; i < N; i += 256) lab[i] = labels[i];
    __syncthreads();

    // row r's u in registers (16 x float4)
    float4 urv[16];
    const float4* urf = (const float4*)ur;
    #pragma unroll
    for (int k = 0; k < 16; ++k) urv[k] = urf[k];

    // 512 dots of length 64; 2 per thread, reads served by L2
    for (int n = tid; n < N; n += 256) {
        const float4* un = (const float4*)(u + (size_t)n * BIT);
        float s = 0.0f;
        #pragma unroll
        for (int k = 0; k < 16; ++k) {
            float4 a = un[k];
            float4 b = urv[k];
            s += a.x * b.x + a.y * b.y + a.z * b.z + a.w * b.w;
        }
        d[n] = s;
    }

    // loss2 partial for row r (wave 0 only; ur already in LDS)
    if (tid < 64) {
        float v = ur[tid];
        float sg = (v > 0.0f) ? 1.0f : ((v < 0.0f) ? -1.0f : 0.0f);
        float dd = v - sg;
        float s2 = dd * dd;
        for (int off = 32; off > 0; off >>= 1) s2 += __shfl_down(s2, off, 64);
        if (tid == 0) atomicAdd(&acc[2], s2);
    }
    __syncthreads();

    int lr = lab[r];
    for (int i = tid; i < N; i += 256) {
        if (lab[i] == lr) {
            int idx = atomicAdd(&npos_s, 1);
            poslist[idx] = i;
        }
    }
    __syncthreads();

    int npos = npos_s;
    int nneg = N - npos;

    float fsum = 0.0f;
    for (int pi = 0; pi < npos; ++pi) {
        float dp = d[poslist[pi]];
        for (int n = tid; n < N; n += 256) {
            if (lab[n] != lr) {
                float t = dp - d[n] - ALPHA;
                t = fminf(fmaxf(t, -100.0f), 50.0f);
                // f = log1p(exp(t)) - t, numerically stable split
                float f = (t > 0.0f) ? log1pf(expf(-t))
                                     : (log1pf(expf(t)) - t);
                fsum += f;
            }
        }
    }

    for (int off = 32; off > 0; off >>= 1) fsum += __shfl_down(fsum, off, 64);
    if ((tid & 63) == 0) wsum[tid >> 6] = fsum;
    __syncthreads();

    if (tid == 0) {
        float total = wsum[0] + wsum[1] + wsum[2] + wsum[3];
        bool valid = (npos > 0) && (nneg > 0);
        float pair_count = fmaxf((float)npos * (float)nneg, 1.0f);
        if (valid) {
            atomicAdd(&acc[0], total / pair_count);
            atomicAdd(&acc[1], 1.0f);
        }
        __threadfence();                       // publish before signaling done
        int done = atomicAdd(ctr, 1);
        if (done == N - 1) {
            // last block: read via atomic round-trip (device-scope visibility)
            float s1  = atomicAdd(&acc[0], 0.0f);
            float cnt = atomicAdd(&acc[1], 0.0f);
            float s2  = atomicAdd(&acc[2], 0.0f);
            float loss1 = (cnt > 0.0f) ? (s1 / fmaxf(cnt, 1.0f)) : 0.0f;
            out[0] = loss1 + LAM * s2 / (float)(N * BIT);
        }
    }
}

extern "C" void kernel_launch(void* const* d_in, const int* in_sizes, int n_in,
                              void* d_out, int out_size, void* d_ws, size_t ws_size,
                              hipStream_t stream) {
    const float* u = (const float*)d_in[0];   // [512, 64]
    const float* y = (const float*)d_in[1];   // [512, 100]
    float* out = (float*)d_out;               // scalar

    char* ws = (char*)d_ws;
    float* acc    = (float*)ws;               // 3 floats
    int*   ctr    = (int*)(ws + 12);          // done counter
    int*   labels = (int*)(ws + 64);          // N ints

    hipMemsetAsync(ws, 0, 64, stream);        // zero acc + ctr (ws is poisoned)

    label_kernel<<<8, 64, 0, stream>>>(y, labels);
    fused_kernel<<<N, 256, 0, stream>>>(u, labels, acc, ctr, out);
}

// Round 3
// 92.770 us; speedup vs baseline: 1.0030x; 1.0030x over previous
//
#include <hip/hip_runtime.h>
#include <hip/hip_bf16.h>
#include <math.h>

#define N 512
#define BIT 64
#define NUM_CLASSES 100
#define ALPHA 5.0f
#define LAM 1.0f

// ws layout: float row_loss[N]; float valid[N]; float sum2[N]
// All written unconditionally by fused_kernel (plain stores, no init needed).

// ---------------------------------------------------------------------------
// fused: one block per row r, 256 threads. Self-contained:
//   labels from one-hot y (lbl = sum_c y[n,c]*c), dots from u (L2-resident),
//   positive compaction, pos x neg softplus sum, per-row loss2 partial.
//   Plain stores of per-row results -> deterministic, no atomics, no init.
// ---------------------------------------------------------------------------
__global__ void fused_kernel(const float* __restrict__ u,
                             const float* __restrict__ y,
                             float* __restrict__ row_loss,
                             float* __restrict__ valid,
                             float* __restrict__ sum2) {
    int r = blockIdx.x;
    int tid = threadIdx.x;

    __shared__ float ur[BIT];
    __shared__ float d[N];
    __shared__ int   lab[N];
    __shared__ int   poslist[N];
    __shared__ int   npos_s;
    __shared__ float wsum[4];

    if (tid == 0) npos_s = 0;
    if (tid < BIT) ur[tid] = u[(size_t)r * BIT + tid];

    // labels: 2 rows per thread; one-hot -> label = sum_c y[n,c] * c
    #pragma unroll
    for (int rep = 0; rep < 2; ++rep) {
        int n = tid + rep * 256;
        const float4* yn = (const float4*)(y + (size_t)n * NUM_CLASSES);
        float s = 0.0f;
        #pragma unroll
        for (int j = 0; j < NUM_CLASSES / 4; ++j) {
            float4 a = yn[j];
            float c0 = (float)(4 * j);
            s += a.x * c0 + a.y * (c0 + 1.0f) + a.z * (c0 + 2.0f) + a.w * (c0 + 3.0f);
        }
        lab[n] = (int)(s + 0.5f);
    }
    __syncthreads();

    // row r's u in registers
    float4 urv[16];
    const float4* urf = (const float4*)ur;
    #pragma unroll
    for (int k = 0; k < 16; ++k) urv[k] = urf[k];

    // 512 dots of length 64 (2 per thread), reads served by L2
    for (int n = tid; n < N; n += 256) {
        const float4* un = (const float4*)(u + (size_t)n * BIT);
        float s = 0.0f;
        #pragma unroll
        for (int k = 0; k < 16; ++k) {
            float4 a = un[k];
            float4 b = urv[k];
            s += a.x * b.x + a.y * b.y + a.z * b.z + a.w * b.w;
        }
        d[n] = s;
    }

    // loss2 partial for row r (wave 0; ur already in LDS)
    if (tid < 64) {
        float v = ur[tid];
        float sg = (v > 0.0f) ? 1.0f : ((v < 0.0f) ? -1.0f : 0.0f);
        float dd = v - sg;
        float s2 = dd * dd;
        for (int off = 32; off > 0; off >>= 1) s2 += __shfl_down(s2, off, 64);
        if (tid == 0) sum2[r] = s2;
    }
    __syncthreads();

    int lr = lab[r];
    for (int i = tid; i < N; i += 256) {
        if (lab[i] == lr) {
            int idx = atomicAdd(&npos_s, 1);   // LDS atomic (order-free: list only)
            poslist[idx] = i;
        }
    }
    __syncthreads();

    int npos = npos_s;
    int nneg = N - npos;

    float fsum = 0.0f;
    for (int pi = 0; pi < npos; ++pi) {
        float dp = d[poslist[pi]];
        for (int n = tid; n < N; n += 256) {
            if (lab[n] != lr) {
                float t = dp - d[n] - ALPHA;
                t = fminf(fmaxf(t, -100.0f), 50.0f);
                // f = log1p(exp(t)) - t, numerically stable split
                float f = (t > 0.0f) ? log1pf(expf(-t))
                                     : (log1pf(expf(t)) - t);
                fsum += f;
            }
        }
    }

    for (int off = 32; off > 0; off >>= 1) fsum += __shfl_down(fsum, off, 64);
    if ((tid & 63) == 0) wsum[tid >> 6] = fsum;
    __syncthreads();

    if (tid == 0) {
        float total = wsum[0] + wsum[1] + wsum[2] + wsum[3];
        bool v = (npos > 0) && (nneg > 0);
        float pair_count = fmaxf((float)npos * (float)nneg, 1.0f);
        row_loss[r] = v ? (total / pair_count) : 0.0f;
        valid[r]   = v ? 1.0f : 0.0f;
    }
}

// ---------------------------------------------------------------------------
// finish: 1 block x 512 threads, deterministic reduction of per-row partials
// ---------------------------------------------------------------------------
__global__ void finish_kernel(const float* __restrict__ row_loss,
                              const float* __restrict__ valid,
                              const float* __restrict__ sum2,
                              float* __restrict__ out) {
    int tid = threadIdx.x;
    __shared__ float w0[8], w1[8], w2[8];

    float a = row_loss[tid];
    float b = valid[tid];
    float c = sum2[tid];
    for (int off = 32; off > 0; off >>= 1) {
        a += __shfl_down(a, off, 64);
        b += __shfl_down(b, off, 64);
        c += __shfl_down(c, off, 64);
    }
    if ((tid & 63) == 0) {
        int w = tid >> 6;
        w0[w] = a; w1[w] = b; w2[w] = c;
    }
    __syncthreads();
    if (tid == 0) {
        float s1 = 0.0f, cnt = 0.0f, s2 = 0.0f;
        #pragma unroll
        for (int w = 0; w < 8; ++w) { s1 += w0[w]; cnt += w1[w]; s2 += w2[w]; }
        float loss1 = (cnt > 0.0f) ? (s1 / fmaxf(cnt, 1.0f)) : 0.0f;
        out[0] = loss1 + LAM * s2 / (float)(N * BIT);
    }
}

extern "C" void kernel_launch(void* const* d_in, const int* in_sizes, int n_in,
                              void* d_out, int out_size, void* d_ws, size_t ws_size,
                              hipStream_t stream) {
    const float* u = (const float*)d_in[0];   // [512, 64]
    const float* y = (const float*)d_in[1];   // [512, 100]
    float* out = (float*)d_out;               // scalar

    char* ws = (char*)d_ws;
    float* row_loss = (float*)ws;                       // N floats
    float* valid    = (float*)(ws + N * sizeof(float)); // N floats
    float* sum2     = (float*)(ws + 2 * N * sizeof(float));

    fused_kernel<<<N, 256, 0, stream>>>(u, y, row_loss, valid, sum2);
    finish_kernel<<<1, 512, 0, stream>>>(row_loss, valid, sum2, out);
}